// Round 1
// baseline (685.454 us; speedup 1.0000x reference)
//
#include <hip/hip_runtime.h>

#define NBMOL 2048
#define NL 128
#define ND 256

constexpr float NEG_SLOPE = 0.2f;
constexpr float LN_EPS = 1e-5f;

typedef __attribute__((ext_vector_type(8))) short short8;
typedef __attribute__((ext_vector_type(4))) float f32x4;

__device__ __forceinline__ unsigned short f2bf(float f) {
  unsigned int u = __float_as_uint(f);
  u = (u + 0x7FFFu + ((u >> 16) & 1u)) >> 16;   // RNE
  return (unsigned short)u;
}
__device__ __forceinline__ float bf2f(unsigned short h) {
  return __uint_as_float(((unsigned int)h) << 16);
}
// swizzled LDS byte offset for bf16 row-major [row][k] tile with 512B rows
__device__ __forceinline__ int swz(int row, int kbyte) {
  return row * 512 + (kbyte ^ ((row & 7) << 4));
}

// ---------------- pre-kernel 1: W2 (fp32 row-major) -> bf16 fragment order ----
// out element index: ((ks*16 + nt)*64 + lane)*8 + j
// value = W2[(lane&15) + nt*16][(lane>>4)*8 + ks*32 + j]
__global__ __launch_bounds__(256) void pack_w2_kernel(const float* __restrict__ W2,
                                                      unsigned short* __restrict__ w2f) {
  int g = blockIdx.x * 256 + threadIdx.x;      // 0..16383
  int ks = g >> 10;
  int nt = (g >> 6) & 15;
  int l  = g & 63;
  int row = (l & 15) + nt * 16;
  int kb  = ((l >> 4) << 3) + ks * 32;
  const float* src = W2 + row * 256 + kb;
  unsigned short h[8];
#pragma unroll
  for (int j = 0; j < 8; ++j) h[j] = f2bf(src[j]);
  unsigned short* dst = w2f + (size_t)g * 8;
#pragma unroll
  for (int j = 0; j < 8; ++j) dst[j] = h[j];
}

// ---------------- pre-kernel 2: q = mol @ W1^T + b1 --------------------------
__global__ __launch_bounds__(256) void compute_q_kernel(const float* __restrict__ mol,
                                                        const float* __restrict__ W1,
                                                        const float* __restrict__ b1,
                                                        float* __restrict__ q) {
  __shared__ float mol_s[8][ND];
  const int t = threadIdx.x;        // = d
  const int b0 = blockIdx.x * 8;
#pragma unroll
  for (int i = 0; i < 8; ++i) mol_s[i][t] = mol[(size_t)(b0 + i) * ND + t];
  __syncthreads();
  float acc[8];
#pragma unroll
  for (int i = 0; i < 8; ++i) acc[i] = 0.f;
  const float4* wrow = (const float4*)(W1 + (size_t)t * ND);
  for (int k4 = 0; k4 < 64; ++k4) {
    float4 w = wrow[k4];
#pragma unroll
    for (int bb = 0; bb < 8; ++bb) {
      float4 m = *(const float4*)&mol_s[bb][k4 * 4];
      acc[bb] += w.x * m.x + w.y * m.y + w.z * m.z + w.w * m.w;
    }
  }
  float bias = b1[t];
#pragma unroll
  for (int bb = 0; bb < 8; ++bb) q[(size_t)(b0 + bb) * ND + t] = acc[bb] + bias;
}

// ---------------- main fused kernel ------------------------------------------
// grid = 256 persistent blocks, 512 threads (8 waves: 2 x 4 wave tiles of 64x64)
__global__ __launch_bounds__(512) void fused_kernel(
    const float* __restrict__ atom,      // [B,L,D] fp32
    const float* __restrict__ attend,    // [B,L]
    const float* __restrict__ smask,     // [B,L]
    const float* __restrict__ w_align,   // [D]
    const float* __restrict__ b_align,   // [1]
    const float* __restrict__ b2,        // [D]
    const float* __restrict__ gamma_,    // [D]
    const float* __restrict__ beta_,     // [D]
    const unsigned short* __restrict__ w2f, // fragment-order bf16 W2
    const float* __restrict__ qbuf,      // [B,D] fp32
    float* __restrict__ out)             // [B,D] fp32
{
  __shared__ unsigned short Abuf[2][NL * ND];   // 2 x 64 KB (A tile, then nb)
  __shared__ float scores_s[NL];
  __shared__ float attn_s[NL];
  __shared__ float ctx_s[2][ND];
  __shared__ float red_s[2][4];

  const int tid  = threadIdx.x;
  const int lane = tid & 63;
  const int wid  = tid >> 6;
  const int wr   = wid >> 2;     // 0..1  (row half)
  const int wc   = wid & 3;      // 0..3  (col quarter)
  const int pidx = blockIdx.x;   // 0..255

  float b2v[4];
#pragma unroll
  for (int nn = 0; nn < 4; ++nn) b2v[nn] = b2[wc * 64 + nn * 16 + (lane & 15)];

  float4 stg[16];
  {
    const float4* src = (const float4*)(atom + (size_t)pidx * (NL * ND));
#pragma unroll
    for (int i = 0; i < 16; ++i) stg[i] = src[i * 512 + tid];
  }

  int cur = 0;
  for (int it = 0; it < 8; ++it) {
    const int b = it * 256 + pidx;

    // ---- write staged A tile (fp32 regs -> bf16 LDS, swizzled) ----
#pragma unroll
    for (int i = 0; i < 16; ++i) {
      int f = i * 512 + tid;           // float4 index
      int row = f >> 6;                // 64 float4 per row
      int kbyte = (f & 63) * 8;        // 4 floats -> 8 bytes bf16
      char* dst = (char*)(&Abuf[cur][0]) + swz(row, kbyte);
      ushort4 hv;
      hv.x = f2bf(stg[i].x); hv.y = f2bf(stg[i].y);
      hv.z = f2bf(stg[i].z); hv.w = f2bf(stg[i].w);
      *(ushort4*)dst = hv;
    }
    __syncthreads();

    // ---- issue next molecule's loads (overlap with GEMM) ----
    if (it < 7) {
      const float4* src = (const float4*)(atom + (size_t)(b + 256) * (NL * ND));
#pragma unroll
      for (int i = 0; i < 16; ++i) stg[i] = src[i * 512 + tid];
    }

    // ---- GEMM: nb = A @ W2^T  (bf16 MFMA 16x16x32) ----
    f32x4 acc[4][4];
#pragma unroll
    for (int mm = 0; mm < 4; ++mm)
#pragma unroll
      for (int nn = 0; nn < 4; ++nn) acc[mm][nn] = {0.f, 0.f, 0.f, 0.f};

#pragma unroll
    for (int ks = 0; ks < 8; ++ks) {
      short8 bfr[4], afr[4];
#pragma unroll
      for (int nn = 0; nn < 4; ++nn) {
        const unsigned short* srcb =
            w2f + ((size_t)((ks * 16 + (wc * 4 + nn)) * 64 + lane)) * 8;
        bfr[nn] = *(const short8*)srcb;
      }
#pragma unroll
      for (int mm = 0; mm < 4; ++mm) {
        int row = wr * 64 + mm * 16 + (lane & 15);
        int kbyte = ((lane >> 4) << 4) + ks * 64;
        afr[mm] = *(const short8*)((const char*)(&Abuf[cur][0]) + swz(row, kbyte));
      }
#pragma unroll
      for (int mm = 0; mm < 4; ++mm)
#pragma unroll
        for (int nn = 0; nn < 4; ++nn)
          acc[mm][nn] = __builtin_amdgcn_mfma_f32_16x16x32_bf16(
              afr[mm], bfr[nn], acc[mm][nn], 0, 0, 0);
    }
    __syncthreads();   // all A-frag reads of Abuf[cur] done

    // ---- write nb (+b2) back into Abuf[cur] as bf16 ----
    // D layout: col = lane&15, row = (lane>>4)*4 + r   [m89-verified]
#pragma unroll
    for (int mm = 0; mm < 4; ++mm) {
#pragma unroll
      for (int nn = 0; nn < 4; ++nn) {
        int col = wc * 64 + nn * 16 + (lane & 15);
#pragma unroll
        for (int r = 0; r < 4; ++r) {
          int row = wr * 64 + mm * 16 + ((lane >> 4) << 2) + r;
          *(unsigned short*)((char*)(&Abuf[cur][0]) + swz(row, col * 2)) =
              f2bf(acc[mm][nn][r] + b2v[nn]);
        }
      }
    }
    __syncthreads();

    // ---- score[l] = sum_d lrelu(q[d] + nb[l,d]) * w_align[d] ----
    {
      const int l = tid >> 2;
      const int pp = tid & 3;
      const float* qrow = qbuf + (size_t)b * ND;
      float s = 0.f;
#pragma unroll
      for (int c = 0; c < 8; ++c) {
        int d0 = pp * 64 + c * 8;
        short8 v = *(const short8*)((const char*)(&Abuf[cur][0]) + swz(l, d0 * 2));
        float4 qa = *(const float4*)(qrow + d0);
        float4 qb = *(const float4*)(qrow + d0 + 4);
        float4 wa = *(const float4*)(w_align + d0);
        float4 wb = *(const float4*)(w_align + d0 + 4);
        float qv[8] = {qa.x, qa.y, qa.z, qa.w, qb.x, qb.y, qb.z, qb.w};
        float wv[8] = {wa.x, wa.y, wa.z, wa.w, wb.x, wb.y, wb.z, wb.w};
#pragma unroll
        for (int j = 0; j < 8; ++j) {
          float t2 = qv[j] + bf2f((unsigned short)v[j]);
          float lr = t2 >= 0.f ? t2 : NEG_SLOPE * t2;
          s += lr * wv[j];
        }
      }
      s += __shfl_xor(s, 1);
      s += __shfl_xor(s, 2);
      if (pp == 0) scores_s[l] = s;
    }
    __syncthreads();

    // ---- softmax over L (wave 0) ----
    if (wid == 0) {
      const float ba = b_align[0];
      float s0 = scores_s[lane]      + ba + smask[(size_t)b * NL + lane];
      float s1 = scores_s[lane + 64] + ba + smask[(size_t)b * NL + lane + 64];
      float m = fmaxf(s0, s1);
#pragma unroll
      for (int o = 32; o > 0; o >>= 1) m = fmaxf(m, __shfl_xor(m, o));
      float e0 = expf(s0 - m), e1 = expf(s1 - m);
      float sum = e0 + e1;
#pragma unroll
      for (int o = 32; o > 0; o >>= 1) sum += __shfl_xor(sum, o);
      float inv = 1.f / sum;
      attn_s[lane]      = e0 * inv * attend[(size_t)b * NL + lane];
      attn_s[lane + 64] = e1 * inv * attend[(size_t)b * NL + lane + 64];
    }
    __syncthreads();

    // ---- ctx[d] = sum_l attn[l] * nb[l,d] ----
    {
      const int d = tid >> 1;
      const int h = tid & 1;
      float s = 0.f;
#pragma unroll 8
      for (int li = 0; li < 64; ++li) {
        int l = h * 64 + li;
        unsigned short v =
            *(const unsigned short*)((const char*)(&Abuf[cur][0]) + swz(l, d * 2));
        s += attn_s[l] * bf2f(v);
      }
      ctx_s[h][d] = s;
    }
    __syncthreads();

    // ---- LayerNorm over D ----
    if (tid < 256) {
      float v = ctx_s[0][tid] + ctx_s[1][tid];
      float sv = v, sq = v * v;
#pragma unroll
      for (int o = 32; o > 0; o >>= 1) {
        sv += __shfl_xor(sv, o);
        sq += __shfl_xor(sq, o);
      }
      if (lane == 0) { red_s[0][wid] = sv; red_s[1][wid] = sq; }
    }
    __syncthreads();
    if (tid < 256) {
      float v = ctx_s[0][tid] + ctx_s[1][tid];
      float sv = red_s[0][0] + red_s[0][1] + red_s[0][2] + red_s[0][3];
      float sq = red_s[1][0] + red_s[1][1] + red_s[1][2] + red_s[1][3];
      float mu = sv * (1.0f / 256.0f);
      float var = fmaxf(sq * (1.0f / 256.0f) - mu * mu, 0.f);
      out[(size_t)b * ND + tid] =
          (v - mu) * rsqrtf(var + LN_EPS) * gamma_[tid] + beta_[tid];
    }
    __syncthreads();

    cur ^= 1;
  }
}

extern "C" void kernel_launch(void* const* d_in, const int* in_sizes, int n_in,
                              void* d_out, int out_size, void* d_ws, size_t ws_size,
                              hipStream_t stream) {
  const float* mol     = (const float*)d_in[0];
  const float* atom    = (const float*)d_in[1];
  const float* attend  = (const float*)d_in[2];
  const float* smask   = (const float*)d_in[3];
  const float* W1      = (const float*)d_in[4];
  const float* b1      = (const float*)d_in[5];
  const float* W2      = (const float*)d_in[6];
  const float* b2      = (const float*)d_in[7];
  const float* w_align = (const float*)d_in[8];
  const float* b_align = (const float*)d_in[9];
  const float* gamma_  = (const float*)d_in[10];
  const float* beta_   = (const float*)d_in[11];
  float* out = (float*)d_out;

  float* qbuf = (float*)d_ws;                                  // 2 MB
  unsigned short* w2f = (unsigned short*)((char*)d_ws + (size_t)NBMOL * ND * 4); // 128 KB

  pack_w2_kernel<<<64, 256, 0, stream>>>(W2, w2f);
  compute_q_kernel<<<256, 256, 0, stream>>>(mol, W1, b1, qbuf);
  fused_kernel<<<256, 512, 0, stream>>>(atom, attend, smask, w_align, b_align,
                                        b2, gamma_, beta_, w2f, qbuf, out);
}

// Round 2
// 458.211 us; speedup vs baseline: 1.4959x; 1.4959x over previous
//
#include <hip/hip_runtime.h>

#define NBMOL 2048
#define NL 128
#define ND 256

constexpr float NEG_SLOPE = 0.2f;
constexpr float LN_EPS = 1e-5f;

typedef __attribute__((ext_vector_type(8))) short short8;
typedef __attribute__((ext_vector_type(4))) float f32x4;

__device__ __forceinline__ unsigned short f2bf(float f) {
  unsigned int u = __float_as_uint(f);
  u = (u + 0x7FFFu + ((u >> 16) & 1u)) >> 16;   // RNE
  return (unsigned short)u;
}
__device__ __forceinline__ float bf2f(unsigned short h) {
  return __uint_as_float(((unsigned int)h) << 16);
}
// swizzled LDS byte offset for bf16 row-major [row][256] tile (512B rows)
__device__ __forceinline__ int swz(int row, int kbyte) {
  return row * 512 + (kbyte ^ ((row & 7) << 4));
}

// ---- pre-kernel 1: W2 fp32 -> (a) bf16 MFMA-fragment order, (b) bf16 row-major
// 8192 threads; g = (ks*16 + nt)*64 + lane, ks in 0..7
__global__ __launch_bounds__(256) void pack_w2_kernel(const float* __restrict__ W2,
                                                      unsigned short* __restrict__ w2f,
                                                      unsigned short* __restrict__ w2p) {
  int g = blockIdx.x * 256 + threadIdx.x;      // 0..8191
  int ks = g >> 10;                            // 0..7
  int nt = (g >> 6) & 15;
  int l  = g & 63;
  int row = (l & 15) + nt * 16;                // output-feature row of W2
  int kb  = ((l >> 4) << 3) + ks * 32;         // k offset
  const float* src = W2 + row * 256 + kb;
  unsigned short h[8];
#pragma unroll
  for (int j = 0; j < 8; ++j) h[j] = f2bf(src[j]);
  unsigned short* dst = w2f + (size_t)g * 8;
#pragma unroll
  for (int j = 0; j < 8; ++j) dst[j] = h[j];
  unsigned short* dst2 = w2p + (size_t)row * 256 + kb;
#pragma unroll
  for (int j = 0; j < 8; ++j) dst2[j] = h[j];
}

// ---- pre-kernel 2: q = mol @ W1^T + b1 ----
__global__ __launch_bounds__(256) void compute_q_kernel(const float* __restrict__ mol,
                                                        const float* __restrict__ W1,
                                                        const float* __restrict__ b1,
                                                        float* __restrict__ q) {
  __shared__ float mol_s[8][ND];
  const int t = threadIdx.x;
  const int b0 = blockIdx.x * 8;
#pragma unroll
  for (int i = 0; i < 8; ++i) mol_s[i][t] = mol[(size_t)(b0 + i) * ND + t];
  __syncthreads();
  float acc[8];
#pragma unroll
  for (int i = 0; i < 8; ++i) acc[i] = 0.f;
  const float4* wrow = (const float4*)(W1 + (size_t)t * ND);
  for (int k4 = 0; k4 < 64; ++k4) {
    float4 w = wrow[k4];
#pragma unroll
    for (int bb = 0; bb < 8; ++bb) {
      float4 m = *(const float4*)&mol_s[bb][k4 * 4];
      acc[bb] += w.x * m.x + w.y * m.y + w.z * m.z + w.w * m.w;
    }
  }
  float bias = b1[t];
#pragma unroll
  for (int bb = 0; bb < 8; ++bb) q[(size_t)(b0 + bb) * ND + t] = acc[bb] + bias;
}

// ---- main fused kernel: one molecule per block, 512 threads, 2 blocks/CU ----
__global__ __launch_bounds__(512, 4) void fused_kernel(
    const float* __restrict__ atom,      // [B,L,D] fp32
    const float* __restrict__ attend,    // [B,L]
    const float* __restrict__ smask,     // [B,L]
    const float* __restrict__ w_align,   // [D]
    const float* __restrict__ b_align,   // [1]
    const float* __restrict__ b2,        // [D]
    const float* __restrict__ gamma_,    // [D]
    const float* __restrict__ beta_,     // [D]
    const unsigned short* __restrict__ w2f,  // frag-order bf16 W2
    const unsigned short* __restrict__ w2p,  // row-major bf16 W2
    const float* __restrict__ qbuf,      // [B,D] fp32
    float* __restrict__ out)             // [B,D] fp32
{
  __shared__ unsigned short Abuf[NL * ND];     // 64 KB bf16 atom tile (swizzled)
  __shared__ float sp_s[4][NL];                // per-wave-quarter score partials
  __shared__ float attn_s[NL];
  __shared__ float ctx4_s[4][ND];              // attn^T@A partials (4 l-quarters)
  __shared__ float y_s[ND];
  __shared__ float gemv_s[2][ND];
  __shared__ float red_s[2][4];
  __shared__ float t_s;                        // sum of attn

  const int tid  = threadIdx.x;
  const int lane = tid & 63;
  const int wid  = tid >> 6;
  const int wr   = wid >> 2;     // 0..1 row half of L
  const int wc   = wid & 3;      // 0..3 col quarter of D
  const int b    = blockIdx.x;

  // ---- stage atom tile fp32 -> bf16 LDS (swizzled), coalesced ----
  {
    const float4* src = (const float4*)(atom + (size_t)b * (NL * ND));
#pragma unroll
    for (int half = 0; half < 2; ++half) {
      float4 v[8];
#pragma unroll
      for (int i = 0; i < 8; ++i) v[i] = src[(half * 8 + i) * 512 + tid];
#pragma unroll
      for (int i = 0; i < 8; ++i) {
        int f = (half * 8 + i) * 512 + tid;    // float4 index in tile
        int row = f >> 6;                      // 64 float4 per row
        int kbyte = (f & 63) * 8;              // 4 floats -> 8 bytes bf16
        ushort4 hv;
        hv.x = f2bf(v[i].x); hv.y = f2bf(v[i].y);
        hv.z = f2bf(v[i].z); hv.w = f2bf(v[i].w);
        *(ushort4*)((char*)Abuf + swz(row, kbyte)) = hv;
      }
    }
  }
  __syncthreads();

  // ---- GEMM: nb = A @ W2^T in registers (bf16 MFMA 16x16x32) ----
  f32x4 acc[4][4];
#pragma unroll
  for (int mm = 0; mm < 4; ++mm)
#pragma unroll
    for (int nn = 0; nn < 4; ++nn) acc[mm][nn] = {0.f, 0.f, 0.f, 0.f};

#pragma unroll
  for (int ks = 0; ks < 8; ++ks) {
    short8 bfr[4], afr[4];
#pragma unroll
    for (int nn = 0; nn < 4; ++nn) {
      const unsigned short* srcb =
          w2f + ((size_t)((ks * 16 + (wc * 4 + nn)) * 64 + lane)) * 8;
      bfr[nn] = *(const short8*)srcb;
    }
#pragma unroll
    for (int mm = 0; mm < 4; ++mm) {
      int row = wr * 64 + mm * 16 + (lane & 15);
      int kbyte = ((lane >> 4) << 4) + ks * 64;
      afr[mm] = *(const short8*)((const char*)Abuf + swz(row, kbyte));
    }
#pragma unroll
    for (int mm = 0; mm < 4; ++mm)
#pragma unroll
      for (int nn = 0; nn < 4; ++nn)
        acc[mm][nn] = __builtin_amdgcn_mfma_f32_16x16x32_bf16(
            afr[mm], bfr[nn], acc[mm][nn], 0, 0, 0);
  }

  // ---- scores straight from accumulators (no nb materialization) ----
  // acc[mm][nn][r]: row = wr*64+mm*16+(lane>>4)*4+r, col = wc*64+nn*16+(lane&15)
  {
    float qv[4], wv[4], bv[4];
    const float* qrow = qbuf + (size_t)b * ND;
#pragma unroll
    for (int nn = 0; nn < 4; ++nn) {
      int col = wc * 64 + nn * 16 + (lane & 15);
      qv[nn] = qrow[col];
      wv[nn] = w_align[col];
      bv[nn] = b2[col];
    }
#pragma unroll
    for (int mm = 0; mm < 4; ++mm) {
#pragma unroll
      for (int r = 0; r < 4; ++r) {
        float s = 0.f;
#pragma unroll
        for (int nn = 0; nn < 4; ++nn) {
          float t2 = qv[nn] + acc[mm][nn][r] + bv[nn];
          s += (t2 >= 0.f ? t2 : NEG_SLOPE * t2) * wv[nn];
        }
        s += __shfl_xor(s, 1);
        s += __shfl_xor(s, 2);
        s += __shfl_xor(s, 4);
        s += __shfl_xor(s, 8);
        if ((lane & 15) == 0)
          sp_s[wc][wr * 64 + mm * 16 + ((lane >> 4) << 2) + r] = s;
      }
    }
  }
  __syncthreads();

  // ---- softmax over L (wave 0) ----
  if (wid == 0) {
    const float ba = b_align[0];
    float s0 = sp_s[0][lane] + sp_s[1][lane] + sp_s[2][lane] + sp_s[3][lane]
               + ba + smask[(size_t)b * NL + lane];
    int l1 = lane + 64;
    float s1 = sp_s[0][l1] + sp_s[1][l1] + sp_s[2][l1] + sp_s[3][l1]
               + ba + smask[(size_t)b * NL + l1];
    float m = fmaxf(s0, s1);
#pragma unroll
    for (int o = 32; o > 0; o >>= 1) m = fmaxf(m, __shfl_xor(m, o));
    float e0 = expf(s0 - m), e1 = expf(s1 - m);
    float sum = e0 + e1;
#pragma unroll
    for (int o = 32; o > 0; o >>= 1) sum += __shfl_xor(sum, o);
    float inv = 1.f / sum;
    float a0 = e0 * inv * attend[(size_t)b * NL + lane];
    float a1 = e1 * inv * attend[(size_t)b * NL + l1];
    attn_s[lane] = a0;
    attn_s[l1]   = a1;
    float tl = a0 + a1;
#pragma unroll
    for (int o = 32; o > 0; o >>= 1) tl += __shfl_xor(tl, o);
    if (lane == 0) t_s = tl;
  }
  __syncthreads();

  // ---- y = attn^T @ A  (partials over 4 l-quarters) ----
  {
    const int d2 = tid & 127;      // handles d = 2*d2, 2*d2+1
    const int h  = tid >> 7;       // l-quarter
    float s0 = 0.f, s1 = 0.f;
#pragma unroll 8
    for (int li = 0; li < 32; ++li) {
      int l = h * 32 + li;
      unsigned int v = *(const unsigned int*)((const char*)Abuf + swz(l, d2 * 4));
      float a = attn_s[l];
      s0 += a * bf2f((unsigned short)(v & 0xffffu));
      s1 += a * bf2f((unsigned short)(v >> 16));
    }
    *(float2*)&ctx4_s[h][2 * d2] = make_float2(s0, s1);
  }
  __syncthreads();
  if (tid < ND)
    y_s[tid] = ctx4_s[0][tid] + ctx4_s[1][tid] + ctx4_s[2][tid] + ctx4_s[3][tid];
  __syncthreads();

  // ---- ctx = y @ W2^T + t*b2  (bf16 W2 row-major, fp32 accum) ----
  {
    const int dp = tid & 255;
    const int kh = tid >> 8;       // k half
    const unsigned short* wrow = w2p + (size_t)dp * 256 + kh * 128;
    float s = 0.f;
#pragma unroll
    for (int k8 = 0; k8 < 16; ++k8) {
      short8 w8 = *(const short8*)(wrow + k8 * 8);
      const float* yy = &y_s[kh * 128 + k8 * 8];
#pragma unroll
      for (int j = 0; j < 8; ++j)
        s += bf2f((unsigned short)w8[j]) * yy[j];
    }
    gemv_s[kh][dp] = s;
  }
  __syncthreads();

  // ---- LayerNorm over D ----
  if (tid < ND) {
    float v = gemv_s[0][tid] + gemv_s[1][tid] + t_s * b2[tid];
    float sv = v, sq = v * v;
#pragma unroll
    for (int o = 32; o > 0; o >>= 1) {
      sv += __shfl_xor(sv, o);
      sq += __shfl_xor(sq, o);
    }
    if (lane == 0) { red_s[0][wid] = sv; red_s[1][wid] = sq; }
  }
  __syncthreads();
  if (tid < ND) {
    float v = gemv_s[0][tid] + gemv_s[1][tid] + t_s * b2[tid];
    float sv = red_s[0][0] + red_s[0][1] + red_s[0][2] + red_s[0][3];
    float sq = red_s[1][0] + red_s[1][1] + red_s[1][2] + red_s[1][3];
    float mu = sv * (1.0f / 256.0f);
    float var = fmaxf(sq * (1.0f / 256.0f) - mu * mu, 0.f);
    out[(size_t)b * ND + tid] =
        (v - mu) * rsqrtf(var + LN_EPS) * gamma_[tid] + beta_[tid];
  }
}

extern "C" void kernel_launch(void* const* d_in, const int* in_sizes, int n_in,
                              void* d_out, int out_size, void* d_ws, size_t ws_size,
                              hipStream_t stream) {
  const float* mol     = (const float*)d_in[0];
  const float* atom    = (const float*)d_in[1];
  const float* attend  = (const float*)d_in[2];
  const float* smask   = (const float*)d_in[3];
  const float* W1      = (const float*)d_in[4];
  const float* b1      = (const float*)d_in[5];
  const float* W2      = (const float*)d_in[6];
  const float* b2      = (const float*)d_in[7];
  const float* w_align = (const float*)d_in[8];
  const float* b_align = (const float*)d_in[9];
  const float* gamma_  = (const float*)d_in[10];
  const float* beta_   = (const float*)d_in[11];
  float* out = (float*)d_out;

  float* qbuf = (float*)d_ws;                                        // 2 MB
  unsigned short* w2f = (unsigned short*)((char*)d_ws + (size_t)NBMOL * ND * 4);  // 128 KB
  unsigned short* w2p = w2f + 65536;                                 // 128 KB

  pack_w2_kernel<<<32, 256, 0, stream>>>(W2, w2f, w2p);
  compute_q_kernel<<<256, 256, 0, stream>>>(mol, W1, b1, qbuf);
  fused_kernel<<<NBMOL, 512, 0, stream>>>(atom, attend, smask, w_align, b_align,
                                          b2, gamma_, beta_, w2f, w2p, qbuf, out);
}